// Round 10
// baseline (751.439 us; speedup 1.0000x reference)
//
#include <hip/hip_runtime.h>
#include <cstddef>
#include <cstdint>

typedef unsigned short ushort_t;
typedef __attribute__((ext_vector_type(8))) short bf16x8;
typedef __attribute__((ext_vector_type(4))) float f32x4;

#define Bb 256
#define Hh 1024
#define Ff 512
#define Tt 128

// ---------- helpers ----------
__device__ __forceinline__ ushort_t f2bf(float f) {
    unsigned int u = __float_as_uint(f);
    unsigned int r = (u + 0x7FFFu + ((u >> 16) & 1u)) >> 16;
    return (ushort_t)r;
}
__device__ __forceinline__ float sigf(float x)  { return 1.0f / (1.0f + __expf(-x)); }
__device__ __forceinline__ float tanhf_(float x){ return 2.0f / (1.0f + __expf(-2.0f * x)) - 1.0f; }

// LDS-only barrier: drains lgkmcnt but leaves global loads IN FLIGHT across
// the barrier (__syncthreads would force vmcnt(0) — the m97 barrier-drain
// stall). Memory-clobber asm fences compiler reordering of LDS ops.
__device__ __forceinline__ void lds_barrier() {
    asm volatile("s_waitcnt lgkmcnt(0)" ::: "memory");
    __builtin_amdgcn_s_barrier();
    asm volatile("" ::: "memory");
}

// ---------- weight swizzle: row-major fp32 [K][N] -> bf16 B-fragment blocks ----------
// 1KB blocks [ntile][kstep]; within: lane=(koff/8)*16+(n%16), j=koff%8.
// modes 0/1: gate-interleaved ntile = ugroup*4 + gate. mode 2 (Wd): plain.
__global__ void swz(const float* __restrict__ s0, const float* __restrict__ s1,
                    ushort_t* __restrict__ dst, int K, int N, int mode, int total)
{
    int KB = K >> 5;
    for (int idx = blockIdx.x * blockDim.x + threadIdx.x; idx < total;
         idx += gridDim.x * blockDim.x) {
        int blk   = idx >> 9;
        int lane  = (idx >> 3) & 63;
        int j     = idx & 7;
        int ntile = blk / KB;
        int kstep = blk - ntile * KB;
        int k = (kstep << 5) + ((lane >> 4) << 3) + j;
        int n;
        if (mode == 2) n = (ntile << 4) + (lane & 15);
        else           n = ((ntile & 3) << 10) + ((ntile >> 2) << 4) + (lane & 15);
        float v;
        if (mode == 0)      v = s0[(size_t)k * N + n] + s1[(size_t)k * N + n];
        else if (mode == 1) v = (k < 1024) ? s0[(size_t)k * N + n]
                                           : s1[(size_t)(k - 1024) * N + n];
        else                v = s0[(size_t)k * N + n];
        dst[idx] = f2bf(v);
    }
}

// ---------- A0 = [x0 | h0] as bf16, row-major [256][2048] ----------
__global__ void mk_a0(const float* __restrict__ x0, const float* __restrict__ h0,
                      ushort_t* __restrict__ a0)
{
    int idx = blockIdx.x * blockDim.x + threadIdx.x;
    if (idx >= Bb * 2048) return;
    int r = idx >> 11, k = idx & 2047;
    float v = (k < 1024) ? x0[r * 1024 + k] : h0[r * 1024 + k - 1024];
    a0[idx] = f2bf(v);
}

__global__ void zero_bar(int* bar) {
    int i = blockIdx.x * blockDim.x + threadIdx.x;
    if (i < 1024) bar[i] = 0;
}

// bar layout (ints, 128B-spaced lines):
//   bar[g*32] : arrival counter for logical group g = blockIdx&7 (32 blocks).
//   All ops agent-scope RMW -> execute at the coherent point (LLC): converges
//   for ANY block->XCD placement (proven r4).

// ---------- step 0 (K=2048, Mcat streamed): round-2 kernel, proven ----------
__global__ __launch_bounds__(256) void lstm_step(
    const ushort_t* __restrict__ Ap, int K,
    const ushort_t* __restrict__ Bw,
    const float* cin, float* cout,
    ushort_t* __restrict__ seqt,
    const float* __restrict__ bias)
{
    __shared__ __align__(16) ushort_t lA[32 * 512];
    __shared__ __align__(16) ushort_t lB[32 * 512];

    const int tid = threadIdx.x, w = tid >> 6, lane = tid & 63;
    const int id = blockIdx.x;
    const int ntg = ((id & 7) << 3) | (id >> 5);
    const int bt  = (id >> 3) & 3;
    const int r0 = bt << 6, hb = ntg << 4;
    const int wr = w >> 1, wc = w & 1;
    const int KB = K >> 5;

    f32x4 acc[2][2];
    #pragma unroll
    for (int m = 0; m < 2; ++m)
        #pragma unroll
        for (int n = 0; n < 2; ++n) acc[m][n] = (f32x4){0.f, 0.f, 0.f, 0.f};

    const int kp = tid & 31;
    const int q_a = kp & 3, kk_a = kp >> 2;

    for (int kc = 0; kc < K; kc += 256) {
        bf16x8 va[8];
        #pragma unroll
        for (int i = 0; i < 8; ++i) {
            int row = (i << 3) + (tid >> 5);
            va[i] = *(const bf16x8*)(Ap + (size_t)(r0 + row) * K + kc + (kp << 3));
        }
        bf16x8 vb[8];
        #pragma unroll
        for (int i = 0; i < 8; ++i)
            vb[i] = *(const bf16x8*)(Bw +
                ((((size_t)((ntg << 2) + w)) * KB + (kc >> 5) + i) << 9) + (lane << 3));
        #pragma unroll
        for (int i = 0; i < 8; ++i) {
            int row = (i << 3) + (tid >> 5);
            int msub = row >> 4, mm = row & 15;
            int pos = (q_a << 4) | (mm ^ (((kk_a << 2) + q_a) & 15));
            *(bf16x8*)&lA[((((kk_a << 2) + msub) << 6) + pos) << 3] = va[i];
        }
        #pragma unroll
        for (int i = 0; i < 8; ++i)
            *(bf16x8*)&lB[(((i << 2) + w) << 9) + (lane << 3)] = vb[i];
        __syncthreads();

        #pragma unroll
        for (int kk = 0; kk < 8; ++kk) {
            const int qq = lane >> 4, mm = lane & 15;
            const int pos = (qq << 4) | (mm ^ (((kk << 2) + qq) & 15));
            bf16x8 af[2], bfr[2];
            #pragma unroll
            for (int m = 0; m < 2; ++m)
                af[m] = *(const bf16x8*)&lA[((((kk << 2) + (wr << 1) + m) << 6) + pos) << 3];
            #pragma unroll
            for (int n = 0; n < 2; ++n)
                bfr[n] = *(const bf16x8*)&lB[((((kk << 2) + (wc << 1) + n) << 6) + lane) << 3];
            #pragma unroll
            for (int m = 0; m < 2; ++m)
                #pragma unroll
                for (int n = 0; n < 2; ++n)
                    acc[m][n] = __builtin_amdgcn_mfma_f32_16x16x32_bf16(
                        af[m], bfr[n], acc[m][n], 0, 0, 0);
        }
        __syncthreads();
    }

    float* lZ = (float*)lA;
    {
        int q = lane >> 4, nl = lane & 15;
        #pragma unroll
        for (int m = 0; m < 2; ++m)
            #pragma unroll
            for (int n = 0; n < 2; ++n)
                #pragma unroll
                for (int r = 0; r < 4; ++r)
                    lZ[((wr << 5) + (m << 4) + (q << 2) + r) * 68 +
                       (wc << 5) + (n << 4) + nl] = acc[m][n][r];
    }
    __syncthreads();

    #pragma unroll
    for (int i = 0; i < 4; ++i) {
        int idx = (i << 8) + tid;
        int row = idx >> 4, u = idx & 15;
        float zi = lZ[row * 68 +      u] + bias[       hb + u];
        float zf = lZ[row * 68 + 16 + u] + bias[1024 + hb + u];
        float zg = lZ[row * 68 + 32 + u] + bias[2048 + hb + u];
        float zo = lZ[row * 68 + 48 + u] + bias[3072 + hb + u];
        size_t cidx = (size_t)(r0 + row) * Hh + hb + u;
        float cp = cin[cidx];
        float cn = sigf(zf) * cp + sigf(zi) * tanhf_(zg);
        cout[cidx] = cn;
        seqt[cidx] = f2bf(sigf(zo) * tanhf_(cn));
    }
}

// ---------- persistent scan, steps 1..127 — wave-level K-split (8 ntiles x K/4) ----------
// Group g = id&7 owns rows [32g,32g+32); block s = id>>3 owns h-cols [32s,32s+32)
// (Z tile 32x128). r9 skeleton (full-tile LDS staging, full-step prefetch,
// lgkm-only barriers, AGPR-pinned B, proven r4 publish/group-barrier).
// CHANGE vs r9 (one mechanism): wave w computes ALL 8 ntiles for K-quarter
// [256w,256w+256) instead of 2 ntiles for all K. B budget identical
// (8x8=64 frags in AGPR), but af LDS reads drop 64->16 b128/wave (each read
// feeds 16 MFMAs instead of 2) and the 4 long acc chains become 16
// independent accumulators (no dependent-MFMA stalls at 1 wave/SIMD).
// r5's K-split failure causes are absent: staging pipeline untouched;
// partials use row-major skew-4 layout (writes <=2-way, reads aligned f32x4).
// Partials in separate 64KB LDS (total 128KB) -> A-overlay barrier gone.
__global__ __launch_bounds__(256, 1) void lstm_scan(
    ushort_t* __restrict__ seq,
    const ushort_t* __restrict__ Msum,
    const float* __restrict__ bias,
    const float* __restrict__ cin,
    int* __restrict__ bar)
{
    __shared__ __align__(16) ushort_t lA[8][4096];   // full A tile: 64KB
    __shared__ __align__(16) float    lZp[16384];    // 4 partials x 32x128 f32 (64KB)

    const int tid = threadIdx.x, w = tid >> 6, lane = tid & 63;
    const int id = blockIdx.x;
    const int g  = id & 7;           // batch-row group (self-contained scan)
    const int s  = id >> 3;          // 0..31: h-col tile within group
    const int r0 = g << 5;           // 32 batch rows
    const int hb = s << 5;           // 32 h cols
    int* const barw = &bar[g << 5];  // group arrival counter (one line per group)

    // ---- resident B: wave w holds ALL 8 ntiles x its K-quarter; AGPR-pinned ----
    // ntl -> (ul = ntl>>2, gate = ntl&3); global ntile = (2s+ul)*4+gate
    bf16x8 Brg[8][8];
    #pragma unroll
    for (int ntl = 0; ntl < 8; ++ntl) {
        const int gnt = (((s << 1) + (ntl >> 2)) << 2) + (ntl & 3);
        const ushort_t* bp = Msum + (((size_t)((gnt << 5) + (w << 3))) << 9) + (lane << 3);
        #pragma unroll
        for (int kl = 0; kl < 8; ++kl) {
            Brg[ntl][kl] = *(const bf16x8*)(bp + ((size_t)kl << 9));
            asm volatile("" : "+a"(Brg[ntl][kl]));
        }
    }

    // ---- c-state + bias in registers: thread owns row=tid>>3, cols gu4..gu4+3 ----
    const int grow = tid >> 3, gu4 = (tid & 7) << 2;
    float c_reg[4], bi[4], bfv[4], bgv[4], bo[4];
    #pragma unroll
    for (int j = 0; j < 4; ++j) {
        int u = gu4 + j;
        c_reg[j] = cin[(size_t)(r0 + grow) * Hh + hb + u];
        bi[j]  = bias[       hb + u];
        bfv[j] = bias[1024 + hb + u];
        bgv[j] = bias[2048 + hb + u];
        bo[j]  = bias[3072 + hb + u];
    }

    // A staging geometry: piece (c,i): row = i*16 + (tid>>4), k-chunk c, kp = tid&15
    const int kp  = tid & 15;
    const int q_a = kp & 3, kk_a = kp >> 2;
    const int mm_s  = tid >> 4;
    const int pos_s = (q_a << 4) | (mm_s ^ (((kk_a << 2) + q_a) & 15));
    const int lw0   = (((kk_a << 1) << 6) | pos_s) << 3;      // ushort idx; piece i adds 512
    const size_t ga0 = (size_t)(r0 + mm_s) * Hh + (kp << 3);  // global base; piece i adds 1<<14

    // gate-read column base: 4-aligned, j-quad never wraps (&127 with 4-aligned start)
    const int cb = ((gu4 >> 4) << 6) + (gu4 & 15);
    const int rb4 = grow << 2;

    #pragma unroll 1
    for (int t = 1; t < Tt; ++t) {
        const ushort_t* Ap = seq + ((size_t)(t - 1) << 18) + ga0;

        f32x4 acc[2][8];
        #pragma unroll
        for (int m = 0; m < 2; ++m)
            #pragma unroll
            for (int ntl = 0; ntl < 8; ++ntl) acc[m][ntl] = (f32x4){0.f, 0.f, 0.f, 0.f};

        // ---- full-step prefetch: issue ALL 16 A-loads (oldest-first order
        // matches the write order below -> progressive counted vmcnt waits) ----
        bf16x8 rA[8][2];
        #pragma unroll
        for (int c = 0; c < 8; ++c)
            #pragma unroll
            for (int i = 0; i < 2; ++i)
                rA[c][i] = *(const bf16x8*)(Ap + (i << 14) + (c << 7));

        // ---- stage the WHOLE tile; one barrier; then barrier-free MFMA ----
        #pragma unroll
        for (int c = 0; c < 8; ++c)
            #pragma unroll
            for (int i = 0; i < 2; ++i)
                *(bf16x8*)&lA[c][lw0 + (i << 9)] = rA[c][i];
        lds_barrier();

        // ---- MFMA: wave w covers global K32-slots 8w..8w+7 = chunks 2w,2w+1 ----
        {
            const int qq = lane >> 4, mr = lane & 15;
            #pragma unroll
            for (int kl = 0; kl < 8; ++kl) {
                const int kk = kl & 3;
                const ushort_t* lAc = lA[(w << 1) + (kl >> 2)];
                const int pos = (qq << 4) | (mr ^ (((kk << 2) + qq) & 15));
                bf16x8 af0 = *(const bf16x8*)&lAc[((((kk << 1) + 0) << 6) | pos) << 3];
                bf16x8 af1 = *(const bf16x8*)&lAc[((((kk << 1) + 1) << 6) | pos) << 3];
                #pragma unroll
                for (int ntl = 0; ntl < 8; ++ntl) {
                    acc[0][ntl] = __builtin_amdgcn_mfma_f32_16x16x32_bf16(af0, Brg[ntl][kl], acc[0][ntl], 0, 0, 0);
                    acc[1][ntl] = __builtin_amdgcn_mfma_f32_16x16x32_bf16(af1, Brg[ntl][kl], acc[1][ntl], 0, 0, 0);
                }
            }
        }

        // ---- Z partial write into own region, row-major skew-4:
        //      addr = row*128 + (col + 4*row)&127 -> writes 2 lanes/bank (free)
        {
            const int q = lane >> 4, nl = lane & 15;
            float* zw = &lZp[w << 12];
            #pragma unroll
            for (int m = 0; m < 2; ++m)
                #pragma unroll
                for (int ntl = 0; ntl < 8; ++ntl)
                    #pragma unroll
                    for (int r = 0; r < 4; ++r) {
                        int row = (m << 4) + (q << 2) + r;
                        int col = (ntl << 4) + nl;
                        zw[(row << 7) + ((col + (row << 2)) & 127)] = acc[m][ntl][r];
                    }
        }
        lds_barrier();   // all partials visible (also fences af reads vs next staging)

        // ---- 4-partial reduce (aligned f32x4 reads) + gates + publish ----
        {
            f32x4 vi = (f32x4){0.f,0.f,0.f,0.f}, vf = vi, vg = vi, vo = vi;
            #pragma unroll
            for (int p = 0; p < 4; ++p) {
                const float* zp = &lZp[(p << 12) + (grow << 7)];
                vi += *(const f32x4*)&zp[(cb      + rb4) & 127];
                vf += *(const f32x4*)&zp[(cb + 16 + rb4) & 127];
                vg += *(const f32x4*)&zp[(cb + 32 + rb4) & 127];
                vo += *(const f32x4*)&zp[(cb + 48 + rb4) & 127];
            }
            unsigned long long pk = 0;
            #pragma unroll
            for (int j = 0; j < 4; ++j) {
                float zi = vi[j] + bi[j];
                float zf = vf[j] + bfv[j];
                float zg = vg[j] + bgv[j];
                float zo = vo[j] + bo[j];
                float cn = sigf(zf) * c_reg[j] + sigf(zi) * tanhf_(zg);
                c_reg[j] = cn;
                pk |= (unsigned long long)f2bf(sigf(zo) * tanhf_(cn)) << (j << 4);
            }
            __hip_atomic_exchange(
                (unsigned long long*)&seq[((size_t)t << 18) +
                                          (size_t)(r0 + grow) * Hh + hb + gu4],
                pk, __ATOMIC_RELAXED, __HIP_MEMORY_SCOPE_AGENT);
        }

        if (t < Tt - 1) {
            __syncthreads();   // FULL drain: exchanges acked at the coherent point
            if (tid == 0) {
                // per-group barrier: agent-scope RMW arrival + RMW poll on one
                // LLC line (32 writers); no cross-group coupling
                __hip_atomic_fetch_add(barw, 1, __ATOMIC_RELAXED,
                                       __HIP_MEMORY_SCOPE_AGENT);
                int guard = 0;
                while (__hip_atomic_fetch_add(barw, 0, __ATOMIC_RELAXED,
                                              __HIP_MEMORY_SCOPE_AGENT) < (t << 5)
                       && ++guard < 30000)
                    __builtin_amdgcn_s_sleep(2);
            }
            lds_barrier();   // release: nothing outstanding to drain here
        }
    }
}

// ---------- batched emission, XCD-pinned, XOR-swizzled A staging ----------
__global__ __launch_bounds__(256) void emit(
    const ushort_t* __restrict__ seq,
    const ushort_t* __restrict__ Wsw,
    const float* __restrict__ bd,
    float* __restrict__ out)
{
    __shared__ __align__(16) ushort_t lA[2 * 8 * 64 * 8];
    __shared__ __align__(16) ushort_t lB[2 * 8 * 64 * 8];
    const int tid = threadIdx.x, w = tid >> 6, lane = tid & 63;
    const int id = blockIdx.x;
    const int rt = ((id >> 5) << 3) | (id & 7);
    const int ct = (id >> 3) & 3;
    const int r0 = rt << 7, f0 = ct << 7;
    const int wr = w >> 1, wc = w & 1;

    f32x4 acc[4][4];
    #pragma unroll
    for (int m = 0; m < 4; ++m)
        #pragma unroll
        for (int n = 0; n < 4; ++n) acc[m][n] = (f32x4){0.f, 0.f, 0.f, 0.f};

    for (int kc = 0; kc < Hh; kc += 64) {
        #pragma unroll
        for (int i = 0; i < 4; ++i) {
            int p = (i << 8) + tid;
            int row = p >> 3, kpp = p & 7;
            bf16x8 v = *(const bf16x8*)(seq + (size_t)(r0 + row) * Hh + kc + (kpp << 3));
            int kk = kpp >> 2, q = kpp & 3, msub = row >> 4, mm = row & 15;
            int pos = (q << 4) | (mm ^ (((kk << 2) + q) & 15));
            *(bf16x8*)&lA[((((kk << 3) + msub) << 6) + pos) << 3] = v;
        }
        #pragma unroll
        for (int i = 0; i < 4; ++i) {
            int d = (i << 8) + tid;
            int kk = d >> 9, csub = (d >> 6) & 7, ln = d & 63;
            int nt = (ct << 3) + csub;
            bf16x8 v = *(const bf16x8*)(Wsw + (((size_t)(nt * 32 + (kc >> 5) + kk)) << 9) + (ln << 3));
            *(bf16x8*)&lB[d << 3] = v;
        }
        __syncthreads();
        const int qq = lane >> 4, mm = lane & 15;
        #pragma unroll
        for (int kk = 0; kk < 2; ++kk) {
            const int pos = (qq << 4) | (mm ^ (((kk << 2) + qq) & 15));
            bf16x8 af[4], bfr[4];
            #pragma unroll
            for (int m = 0; m < 4; ++m)
                af[m] = *(const bf16x8*)&lA[((((kk << 3) + (wr << 2) + m) << 6) + pos) << 3];
            #pragma unroll
            for (int n = 0; n < 4; ++n)
                bfr[n] = *(const bf16x8*)&lB[((((kk << 3) + (wc << 2) + n) << 6) + lane) << 3];
            #pragma unroll
            for (int m = 0; m < 4; ++m)
                #pragma unroll
                for (int n = 0; n < 4; ++n)
                    acc[m][n] = __builtin_amdgcn_mfma_f32_16x16x32_bf16(
                        af[m], bfr[n], acc[m][n], 0, 0, 0);
        }
        __syncthreads();
    }

    int q = lane >> 4, nl = lane & 15;
    float bdv[4];
    #pragma unroll
    for (int n = 0; n < 4; ++n) bdv[n] = bd[f0 + (wc << 6) + (n << 4) + nl];
    #pragma unroll
    for (int m = 0; m < 4; ++m)
        #pragma unroll
        for (int r = 0; r < 4; ++r) {
            int grow2 = r0 + (wr << 6) + (m << 4) + (q << 2) + r;  // = t*256 + b
            int tt = grow2 >> 8, bb = grow2 & 255;
            float* op = out + ((size_t)((bb << 7) + tt) << 9);
            #pragma unroll
            for (int n = 0; n < 4; ++n)
                op[f0 + (wc << 6) + (n << 4) + nl] = acc[m][n][r] + bdv[n];
        }
}

// ---------- launch ----------
extern "C" void kernel_launch(void* const* d_in, const int* in_sizes, int n_in,
                              void* d_out, int out_size, void* d_ws, size_t ws_size,
                              hipStream_t stream)
{
    const float* x0 = (const float*)d_in[0];
    const float* h0 = (const float*)d_in[1];
    const float* c0 = (const float*)d_in[2];
    const float* W  = (const float*)d_in[3];
    const float* U  = (const float*)d_in[4];
    const float* b  = (const float*)d_in[5];
    const float* Wd = (const float*)d_in[6];
    const float* bd = (const float*)d_in[7];
    float* out = (float*)d_out;

    const size_t OFF_MCAT = 0;                  // 16,777,216
    const size_t OFF_MSUM = 16777216;           //  8,388,608
    const size_t OFF_WSW  = 25165824;           //  1,048,576
    const size_t OFF_A0   = 26214400;           //  1,048,576
    const size_t OFF_SEQ  = 27262976;           // 67,108,864
    const size_t OFF_BAR  = 94371840;           //      4,096
    const size_t WS_NEED  = 94375936;
    if (ws_size < WS_NEED) return;

    char* ws = (char*)d_ws;
    ushort_t* Mcat = (ushort_t*)(ws + OFF_MCAT);
    ushort_t* Msum = (ushort_t*)(ws + OFF_MSUM);
    ushort_t* Wsw  = (ushort_t*)(ws + OFF_WSW);
    ushort_t* A0   = (ushort_t*)(ws + OFF_A0);
    ushort_t* seq  = (ushort_t*)(ws + OFF_SEQ);
    int*      bar  = (int*)(ws + OFF_BAR);
    float* cws = out;   // c-state scratch: dead before emit overwrites out

    zero_bar<<<4, 256, 0, stream>>>(bar);
    mk_a0<<<2048, 256, 0, stream>>>(x0, h0, A0);
    swz<<<4096, 256, 0, stream>>>(W, U, Mcat, 2048, 4096, 1, 2048 * 4096);
    swz<<<2048, 256, 0, stream>>>(W, U, Msum, 1024, 4096, 0, 1024 * 4096);
    swz<<<512, 256, 0, stream>>>(Wd, nullptr, Wsw, 1024, 512, 2, 1024 * 512);

    lstm_step<<<256, 256, 0, stream>>>(A0, 2048, Mcat, c0, cws, seq, b);
    lstm_scan<<<256, 256, 0, stream>>>(seq, Msum, b, cws, bar);

    emit<<<1024, 256, 0, stream>>>(seq, Wsw, bd, out);
}